// Round 1
// baseline (233.246 us; speedup 1.0000x reference)
//
#include <hip/hip_runtime.h>
#include <math.h>

// Problem constants
#define NB   4
#define SEQ  2048
#define NH   12
#define CIN  2304      // 3*768 floats per token
#define TM   64        // kv rows per chunk
#define NCH  (SEQ/TM)  // 32 chunks
#define TQ   128       // q rows per block (4 waves x 32 q)

typedef _Float16 half8 __attribute__((ext_vector_type(8)));
typedef _Float16 half4 __attribute__((ext_vector_type(4)));
typedef float    f32x4 __attribute__((ext_vector_type(4)));
typedef unsigned int u32;
#define AS1 __attribute__((address_space(1)))
#define AS3 __attribute__((address_space(3)))

// K/V tile = 64x64 f16 = 8192 B stored as the EXACT swizzled LDS image
// (row r * 128 B, 16B-group g at g ^ (r&7)).  R7 change: the attention
// kernel now reads MFMA fragments DIRECTLY from these tiles in global
// memory (each 4-lane group = one contiguous 64-B sector), eliminating
// the per-chunk DMA, all K/V ds_reads, and every __syncthreads in the
// main loop (the LDS unit was the hidden ~70%-busy bottleneck).
#define TILE_B  8192
#define KT_BYTES ((size_t)NB*NH*NCH*TILE_B)   // 12,582,912 (K tiles)
#define WS_FULL  (2*KT_BYTES)                 // 25,165,824 (K+V tiles)

static __device__ __forceinline__ int dec_xcd(int id, int& b, int& h, int& q0) {
    // XCD swizzle (R6-validated): all 16 q-tiles of one (b,h) share id%8
    const int xcd = id & 7;
    const int qt  = (id >> 3) & 15;
    const int grp = id >> 7;          // 0..5
    const int bh  = grp * 8 + xcd;    // 0..47
    b = bh / NH; h = bh - b * NH; q0 = qt * TQ;
    return bh;
}

// ---------------------------------------------------------------------------
// Preprocess: LayerNorm K into swizzled f16 tiles (always); V transposed
// tiles too when writeV!=0. Grid (mc,h,b)=(32,12,4), 256 thr.  (R3-validated)
// Left byte-identical in R7 for clean per-dispatch attribution.
// ---------------------------------------------------------------------------
__global__ __launch_bounds__(256, 4)
void preprocess_kernel(const float* __restrict__ QKV,
                       const float* __restrict__ k_scale,
                       const float* __restrict__ k_bias,
                       unsigned char* __restrict__ ws, int writeV)
{
    const int tid = threadIdx.x;
    const int L   = tid & 63;
    const int wv  = tid >> 6;
    const int r4  = L >> 2;
    const int c4  = L & 3;
    const int mc  = blockIdx.x, h = blockIdx.y, b = blockIdx.z;

    unsigned char* Kt = ws + (size_t)((b*NH + h)*NCH + mc) * TILE_B;

    const float4* QKV4 = (const float4*)QKV;
    const int row = wv*16 + r4;
    const size_t base4 = (size_t)(b*SEQ + mc*64 + row) * 576 + h*16 + c4*4;

    {   // K: LN -> swizzled tile image
        float4 x[4];
        #pragma unroll
        for (int i = 0; i < 4; ++i) x[i] = QKV4[base4 + 192 + i];
        float s = 0.f, s2 = 0.f;
        #pragma unroll
        for (int i = 0; i < 4; ++i) {
            s  += x[i].x + x[i].y + x[i].z + x[i].w;
            s2 += x[i].x*x[i].x + x[i].y*x[i].y + x[i].z*x[i].z + x[i].w*x[i].w;
        }
        s  += __shfl_xor(s, 1);  s  += __shfl_xor(s, 2);
        s2 += __shfl_xor(s2, 1); s2 += __shfl_xor(s2, 2);
        float mu = s * 0.015625f;
        float rstd = rsqrtf(s2 * 0.015625f - mu*mu + 1e-6f);
        float nb0 = -mu * rstd;
        half8 h0, h1;
        #pragma unroll
        for (int i = 0; i < 4; ++i) {
            float4 sc = ((const float4*)k_scale)[c4*4 + i];
            float4 bi = ((const float4*)k_bias)[c4*4 + i];
            float e0 = fmaf(x[i].x, rstd, nb0) * sc.x + bi.x;
            float e1 = fmaf(x[i].y, rstd, nb0) * sc.y + bi.y;
            float e2 = fmaf(x[i].z, rstd, nb0) * sc.z + bi.z;
            float e3 = fmaf(x[i].w, rstd, nb0) * sc.w + bi.w;
            if (i < 2) { h0[i*4+0]=(_Float16)e0; h0[i*4+1]=(_Float16)e1; h0[i*4+2]=(_Float16)e2; h0[i*4+3]=(_Float16)e3; }
            else { int j=(i-2)*4; h1[j+0]=(_Float16)e0; h1[j+1]=(_Float16)e1; h1[j+2]=(_Float16)e2; h1[j+3]=(_Float16)e3; }
        }
        *(half8*)(Kt + row*128 + (((2*c4+0) ^ (row & 7)) * 16)) = h0;
        *(half8*)(Kt + row*128 + (((2*c4+1) ^ (row & 7)) * 16)) = h1;
    }

    if (writeV) {   // V: transpose -> swizzled tile (lane = d)
        unsigned char* Vt = ws + KT_BYTES + (size_t)((b*NH + h)*NCH + mc) * TILE_B;
        const float* gv = QKV + (size_t)(b*SEQ + mc*64 + wv*16)*CIN + 1536 + h*64 + L;
        float vvp[16];
        #pragma unroll
        for (int j = 0; j < 16; ++j) vvp[j] = gv[(size_t)j * CIN];
        half8 a0, a1;
        #pragma unroll
        for (int j = 0; j < 8; ++j) { a0[j] = (_Float16)vvp[j]; a1[j] = (_Float16)vvp[j+8]; }
        *(half8*)(Vt + L*128 + (((2*wv+0) ^ (L & 7)) * 16)) = a0;
        *(half8*)(Vt + L*128 + (((2*wv+1) ^ (L & 7)) * 16)) = a1;
    }
}

// Shared Q-prologue + fragment pickup (R6-validated), emitted inline.
#define Q_PROLOGUE(QTBASE)                                                        \
    const float SC = 0.125f * 1.44269504088896340736f;                            \
    _Pragma("unroll")                                                             \
    for (int g = 0; g < 2; ++g) {                                                 \
        const int row = wv*32 + g*16 + r4;                                        \
        const size_t base4 = (size_t)(b*SEQ + q0 + row) * 576 + h*16 + c4*4;      \
        float4 x[4];                                                              \
        _Pragma("unroll")                                                         \
        for (int i = 0; i < 4; ++i) x[i] = QKV4[base4 + i];                       \
        float s = 0.f, s2 = 0.f;                                                  \
        _Pragma("unroll")                                                         \
        for (int i = 0; i < 4; ++i) {                                             \
            s  += x[i].x + x[i].y + x[i].z + x[i].w;                              \
            s2 += x[i].x*x[i].x + x[i].y*x[i].y + x[i].z*x[i].z + x[i].w*x[i].w;  \
        }                                                                         \
        s  += __shfl_xor(s, 1);  s  += __shfl_xor(s, 2);                          \
        s2 += __shfl_xor(s2, 1); s2 += __shfl_xor(s2, 2);                         \
        float mu = s * 0.015625f;                                                 \
        float rstd = rsqrtf(s2 * 0.015625f - mu*mu + 1e-6f);                      \
        float nb0 = -mu * rstd;                                                   \
        half8 h0, h1;                                                             \
        _Pragma("unroll")                                                         \
        for (int i = 0; i < 4; ++i) {                                             \
            float4 sc = ((const float4*)q_scale)[c4*4 + i];                       \
            float4 bi = ((const float4*)q_bias)[c4*4 + i];                        \
            float e0 = (fmaf(x[i].x, rstd, nb0) * sc.x + bi.x) * SC;              \
            float e1 = (fmaf(x[i].y, rstd, nb0) * sc.y + bi.y) * SC;              \
            float e2 = (fmaf(x[i].z, rstd, nb0) * sc.z + bi.z) * SC;              \
            float e3 = (fmaf(x[i].w, rstd, nb0) * sc.w + bi.w) * SC;              \
            if (i < 2) { h0[i*4+0]=(_Float16)e0; h0[i*4+1]=(_Float16)e1; h0[i*4+2]=(_Float16)e2; h0[i*4+3]=(_Float16)e3; } \
            else { int j=(i-2)*4; h1[j+0]=(_Float16)e0; h1[j+1]=(_Float16)e1; h1[j+2]=(_Float16)e2; h1[j+3]=(_Float16)e3; } \
        }                                                                         \
        *(half8*)((QTBASE) + row*128 + (((2*c4+0) ^ (r4 & 7)) * 16)) = h0;        \
        *(half8*)((QTBASE) + row*128 + (((2*c4+1) ^ (r4 & 7)) * 16)) = h1;        \
    }                                                                             \
    half8 qf[2][2];                                                               \
    _Pragma("unroll")                                                             \
    for (int s = 0; s < 2; ++s) {                                                 \
        const unsigned char* qrow = (QTBASE) + (wv*32 + s*16 + n16)*128;          \
        _Pragma("unroll")                                                         \
        for (int ks = 0; ks < 2; ++ks)                                            \
            qf[s][ks] = *(const half8*)(qrow + (((quad + 4*ks) ^ sw) * 16));      \
    }

// Compute body for one chunk given Ka/Vt base pointers (R6-validated):
// fragments read via pointer deref (works for LDS *or* global tiles).
#define CHUNK_COMPUTE(KAB, VTB)                                                   \
    {                                                                             \
        f32x4 sacc[2][4] = {};                                                    \
        _Pragma("unroll")                                                         \
        for (int ks = 0; ks < 2; ++ks) {                                          \
            half8 ak[4];                                                          \
            _Pragma("unroll")                                                     \
            for (int mt = 0; mt < 4; ++mt)                                        \
                ak[mt] = *(const half8*)((KAB) + (16*mt + n16)*128 + (((quad + 4*ks) ^ sw) * 16)); \
            _Pragma("unroll")                                                     \
            for (int s = 0; s < 2; ++s)                                           \
                _Pragma("unroll")                                                 \
                for (int mt = 0; mt < 4; ++mt)                                    \
                    sacc[s][mt] = __builtin_amdgcn_mfma_f32_16x16x32_f16(ak[mt], qf[s][ks], sacc[s][mt], 0, 0, 0); \
        }                                                                         \
        /* Issue all V-fragment loads now: latency hides under softmax. */        \
        half8 av[2][4];                                                           \
        _Pragma("unroll")                                                         \
        for (int ks = 0; ks < 2; ++ks)                                            \
            _Pragma("unroll")                                                     \
            for (int mt = 0; mt < 4; ++mt)                                        \
                av[ks][mt] = *(const half8*)((VTB) + (16*mt + n16)*128 + (((quad + 4*ks) ^ sw) * 16)); \
        _Pragma("unroll")                                                         \
        for (int s = 0; s < 2; ++s) {                                             \
            float ls = 0.f;                                                       \
            _Pragma("unroll")                                                     \
            for (int mt = 0; mt < 4; ++mt) {                                      \
                float p0 = __builtin_exp2f(sacc[s][mt][0]);                       \
                float p1 = __builtin_exp2f(sacc[s][mt][1]);                       \
                float p2 = __builtin_exp2f(sacc[s][mt][2]);                       \
                float p3 = __builtin_exp2f(sacc[s][mt][3]);                       \
                ls += (p0 + p1) + (p2 + p3);                                      \
                half4 hp; hp[0]=(_Float16)p0; hp[1]=(_Float16)p1; hp[2]=(_Float16)p2; hp[3]=(_Float16)p3; \
                *(half4*)(Pw + s*2048 + n16*128 + (((4*mt + quad) ^ n16) * 8)) = hp; \
            }                                                                     \
            ls += __shfl_xor(ls, 16);                                             \
            ls += __shfl_xor(ls, 32);                                             \
            lsum[s] += ls;                                                        \
        }                                                                         \
        _Pragma("unroll")                                                         \
        for (int ks = 0; ks < 2; ++ks) {                                          \
            _Pragma("unroll")                                                     \
            for (int s = 0; s < 2; ++s) {                                         \
                half4 b0 = *(const half4*)(Pw + s*2048 + n16*128 + (((8*ks + 2*quad + 0) ^ n16) * 8)); \
                half4 b1 = *(const half4*)(Pw + s*2048 + n16*128 + (((8*ks + 2*quad + 1) ^ n16) * 8)); \
                half8 bp;                                                         \
                _Pragma("unroll")                                                 \
                for (int j = 0; j < 4; ++j) { bp[j] = b0[j]; bp[4+j] = b1[j]; }   \
                _Pragma("unroll")                                                 \
                for (int mt = 0; mt < 4; ++mt)                                    \
                    oacc[s][mt] = __builtin_amdgcn_mfma_f32_16x16x32_f16(av[ks][mt], bp, oacc[s][mt], 0, 0, 0); \
            }                                                                     \
        }                                                                         \
    }

#define EPILOGUE()                                                                \
    {                                                                             \
        float4* out4 = (float4*)out;                                              \
        _Pragma("unroll")                                                         \
        for (int s = 0; s < 2; ++s) {                                             \
            float inv = 1.0f / lsum[s];                                           \
            size_t rowb = ((size_t)(b*NH + h)*SEQ + q0 + wv*32 + s*16 + n16) * 16;\
            _Pragma("unroll")                                                     \
            for (int mt = 0; mt < 4; ++mt)                                        \
                out4[rowb + mt*4 + quad] = make_float4(oacc[s][mt][0]*inv, oacc[s][mt][1]*inv, oacc[s][mt][2]*inv, oacc[s][mt][3]*inv); \
        }                                                                         \
    }

#define COMMON_IDS()                                                              \
    const int tid  = threadIdx.x;                                                 \
    const int L    = tid & 63;                                                    \
    const int wv   = tid >> 6;                                                    \
    const int n16  = L & 15;                                                      \
    const int quad = L >> 4;                                                      \
    const int sw   = n16 & 7;                                                     \
    const int r4   = L >> 2;                                                      \
    const int c4   = L & 3;                                                       \
    int b, h, q0; dec_xcd(blockIdx.x, b, h, q0);                                  \
    const float4* QKV4 = (const float4*)QKV;

// ---------------------------------------------------------------------------
// Tier (a) R7: barrier-free direct-fragment attention.
// K/V fragments are global_load_dwordx4'd straight from the swizzled tiles
// in workspace (each 4-lane group reads one contiguous 64-B sector; tiles
// are L1/L2-resident thanks to the XCD swizzle clustering all 16 q-tiles
// of a (b,h) on one XCD).  LDS holds only the per-wave Q staging / P
// buffer (16 KB, wave-private) -> zero __syncthreads in the main loop.
// ---------------------------------------------------------------------------
__global__ __launch_bounds__(256, 3)
void attn_direct(const float* __restrict__ QKV,
                 const float* __restrict__ q_scale,
                 const float* __restrict__ q_bias,
                 const unsigned char* __restrict__ ws,
                 float* __restrict__ out)
{
    __shared__ __align__(16) unsigned char sm[16384]; // Qt staging + per-wave P
    COMMON_IDS()
    unsigned char* Qt = sm;
    unsigned char* Pw = Qt + wv*4096;

    const unsigned char* Kt = ws + (size_t)((b*NH + h)*NCH) * TILE_B;
    const unsigned char* Vt = ws + KT_BYTES + (size_t)((b*NH + h)*NCH) * TILE_B;

    Q_PROLOGUE(Qt)

    f32x4 oacc[2][4] = {};
    float lsum[2] = {0.f, 0.f};

    for (int mc = 0; mc < NCH; ++mc, Kt += TILE_B, Vt += TILE_B) {
        CHUNK_COMPUTE(Kt, Vt)
    }
    EPILOGUE()
}

// ---------------------------------------------------------------------------
// Tier (b): K tiles DMA'd (dbuf), V staged in-kernel (R6 path), 2 barriers.
// ---------------------------------------------------------------------------
__global__ __launch_bounds__(256, 3)
void attn_ktile(const float* __restrict__ QKV,
                const float* __restrict__ q_scale,
                const float* __restrict__ q_bias,
                const unsigned char* __restrict__ ws,
                float* __restrict__ out)
{
    __shared__ __align__(16) unsigned char sm[40960]; // Kbuf0 8K|Kbuf1 8K|Vt 8K|Qt/P 16K
    COMMON_IDS()
    unsigned char* Vt = sm + 16384;
    unsigned char* Qt = sm + 24576;
    unsigned char* Pw = Qt + wv*4096;

    const unsigned char* Ktiles = ws + (size_t)((b*NH + h)*NCH) * TILE_B;

    #define ISSUE_K(MC, P)                                                        \
    {                                                                             \
        const unsigned char* kt_ = Ktiles + (size_t)(MC) * TILE_B;                \
        unsigned char* lk_ = sm + (P)*8192;                                       \
        _Pragma("unroll")                                                         \
        for (int t_ = 0; t_ < 2; ++t_) {                                          \
            int seg_ = wv*2 + t_;                                                 \
            __builtin_amdgcn_global_load_lds((const AS1 u32*)(kt_ + seg_*1024 + L*16), \
                                             (AS3 u32*)(lk_ + seg_*1024), 16, 0, 0);   \
        }                                                                         \
    }
    float vv[16];
    #define PREFETCH_V(MC)                                                        \
    {                                                                             \
        const float* gv = QKV + (size_t)(b*SEQ + (MC)*64 + wv*16) * CIN + 1536 + h*64 + L; \
        _Pragma("unroll")                                                         \
        for (int j = 0; j < 16; ++j) vv[j] = gv[(size_t)j * CIN];                 \
    }
    #define STAGE_V()                                                             \
    {                                                                             \
        half8 a0, a1;                                                             \
        _Pragma("unroll")                                                         \
        for (int j = 0; j < 8; ++j) { a0[j] = (_Float16)vv[j]; a1[j] = (_Float16)vv[j+8]; } \
        *(half8*)(Vt + L*128 + (((2*wv+0) ^ (L & 7)) * 16)) = a0;                 \
        *(half8*)(Vt + L*128 + (((2*wv+1) ^ (L & 7)) * 16)) = a1;                 \
    }

    PREFETCH_V(0)
    ISSUE_K(0, 0)
    Q_PROLOGUE(Qt)

    f32x4 oacc[2][4] = {};
    float lsum[2] = {0.f, 0.f};

    for (int mc = 0; mc < NCH; ++mc) {
        const int p = mc & 1;
        __syncthreads();                    // K-DMA(mc) landed; prev Vt reads done
        STAGE_V()
        __syncthreads();                    // Vt visible
        if (mc + 1 < NCH) { ISSUE_K(mc + 1, p ^ 1) PREFETCH_V(mc + 1) }
        const unsigned char* Ka = sm + p*8192;
        CHUNK_COMPUTE(Ka, Vt)
    }
    EPILOGUE()
    #undef ISSUE_K
    #undef PREFETCH_V
    #undef STAGE_V
}

// ---------------------------------------------------------------------------
// Tier (c) fallback: exact R6 fused kernel (validated).
// ---------------------------------------------------------------------------
__global__ __launch_bounds__(256, 3)
void fused_fallback(const float* __restrict__ QKV,
                    const float* __restrict__ q_scale,
                    const float* __restrict__ q_bias,
                    const float* __restrict__ k_scale,
                    const float* __restrict__ k_bias,
                    float* __restrict__ out)
{
    __shared__ __align__(16) unsigned char sm[32768];
    COMMON_IDS()
    unsigned char* Ka = sm;
    unsigned char* Vt = sm + 8192;
    unsigned char* Qt = sm + 16384;
    unsigned char* Pw = Qt + wv*4096;

    float4 ksr[4], kbr[4];
    #pragma unroll
    for (int i = 0; i < 4; ++i) {
        ksr[i] = ((const float4*)k_scale)[c4 * 4 + i];
        kbr[i] = ((const float4*)k_bias)[c4 * 4 + i];
    }
    float4 kx[4];
    float  vv[16];
    #define PREFETCH(MC)                                                          \
    {                                                                             \
        const size_t kb4 = (size_t)(b*SEQ + (MC)*64 + wv*16 + r4) * 576 + 192 + h*16 + c4*4; \
        _Pragma("unroll")                                                         \
        for (int i = 0; i < 4; ++i) kx[i] = QKV4[kb4 + i];                        \
        const float* gv = QKV + (size_t)(b*SEQ + (MC)*64 + wv*16) * CIN + 1536 + h*64 + L; \
        _Pragma("unroll")                                                         \
        for (int j = 0; j < 16; ++j) vv[j] = gv[(size_t)j * CIN];                 \
    }
    #define STAGE_KV()                                                            \
    {                                                                             \
        const int row = wv*16 + r4;                                               \
        float s = 0.f, s2 = 0.f;                                                  \
        _Pragma("unroll")                                                         \
        for (int i = 0; i < 4; ++i) {                                             \
            s  += kx[i].x + kx[i].y + kx[i].z + kx[i].w;                          \
            s2 += kx[i].x*kx[i].x + kx[i].y*kx[i].y + kx[i].z*kx[i].z + kx[i].w*kx[i].w; \
        }                                                                         \
        s  += __shfl_xor(s, 1);  s  += __shfl_xor(s, 2);                          \
        s2 += __shfl_xor(s2, 1); s2 += __shfl_xor(s2, 2);                         \
        float mu = s * 0.015625f;                                                 \
        float rstd = rsqrtf(s2 * 0.015625f - mu*mu + 1e-6f);                      \
        float nb0 = -mu * rstd;                                                   \
        half8 h0, h1;                                                             \
        _Pragma("unroll")                                                         \
        for (int i = 0; i < 4; ++i) {                                             \
            float e0 = fmaf(kx[i].x, rstd, nb0) * ksr[i].x + kbr[i].x;            \
            float e1 = fmaf(kx[i].y, rstd, nb0) * ksr[i].y + kbr[i].y;            \
            float e2 = fmaf(kx[i].z, rstd, nb0) * ksr[i].z + kbr[i].z;            \
            float e3 = fmaf(kx[i].w, rstd, nb0) * ksr[i].w + kbr[i].w;            \
            if (i < 2) { h0[i*4+0]=(_Float16)e0; h0[i*4+1]=(_Float16)e1; h0[i*4+2]=(_Float16)e2; h0[i*4+3]=(_Float16)e3; } \
            else { int j=(i-2)*4; h1[j+0]=(_Float16)e0; h1[j+1]=(_Float16)e1; h1[j+2]=(_Float16)e2; h1[j+3]=(_Float16)e3; } \
        }                                                                         \
        *(half8*)(Ka + row*128 + (((2*c4+0) ^ (row & 7)) * 16)) = h0;             \
        *(half8*)(Ka + row*128 + (((2*c4+1) ^ (row & 7)) * 16)) = h1;             \
        half8 a0, a1;                                                             \
        _Pragma("unroll")                                                         \
        for (int j = 0; j < 8; ++j) { a0[j] = (_Float16)vv[j]; a1[j] = (_Float16)vv[j+8]; } \
        *(half8*)(Vt + L*128 + (((2*wv+0) ^ (L & 7)) * 16)) = a0;                 \
        *(half8*)(Vt + L*128 + (((2*wv+1) ^ (L & 7)) * 16)) = a1;                 \
    }

    PREFETCH(0)
    Q_PROLOGUE(Qt)

    f32x4 oacc[2][4] = {};
    float lsum[2] = {0.f, 0.f};

    for (int mc = 0; mc < NCH; ++mc) {
        __syncthreads();
        STAGE_KV()
        __syncthreads();
        if (mc + 1 < NCH) PREFETCH(mc + 1)
        CHUNK_COMPUTE(Ka, Vt)
    }
    EPILOGUE()
    #undef PREFETCH
    #undef STAGE_KV
}

extern "C" void kernel_launch(void* const* d_in, const int* in_sizes, int n_in,
                              void* d_out, int out_size, void* d_ws, size_t ws_size,
                              hipStream_t stream) {
    const float* QKV     = (const float*)d_in[0];
    const float* q_scale = (const float*)d_in[1];
    const float* q_bias  = (const float*)d_in[2];
    const float* k_scale = (const float*)d_in[3];
    const float* k_bias  = (const float*)d_in[4];
    float* out = (float*)d_out;
    unsigned char* ws = (unsigned char*)d_ws;

    const dim3 agrid(NB * NH * (SEQ / TQ));   // 768 flat, XCD-decoded inside
    if (ws_size >= WS_FULL) {
        preprocess_kernel<<<dim3(NCH, NH, NB), 256, 0, stream>>>(QKV, k_scale, k_bias, ws, 1);
        attn_direct<<<agrid, 256, 0, stream>>>(QKV, q_scale, q_bias, ws, out);
    } else if (ws_size >= KT_BYTES) {
        preprocess_kernel<<<dim3(NCH, NH, NB), 256, 0, stream>>>(QKV, k_scale, k_bias, ws, 0);
        attn_ktile<<<agrid, 256, 0, stream>>>(QKV, q_scale, q_bias, ws, out);
    } else {
        fused_fallback<<<agrid, 256, 0, stream>>>(QKV, q_scale, q_bias, k_scale, k_bias, out);
    }
}

// Round 5
// 217.137 us; speedup vs baseline: 1.0742x; 1.0742x over previous
//
#include <hip/hip_runtime.h>
#include <math.h>

// Problem constants
#define NB   4
#define SEQ  2048
#define NH   12
#define CIN  2304      // 3*768 floats per token
#define TM   64        // kv rows per chunk
#define NCH  (SEQ/TM)  // 32 chunks
#define TQ   128       // q rows per block (4 waves x 32 q)

typedef _Float16 half8 __attribute__((ext_vector_type(8)));
typedef _Float16 half4 __attribute__((ext_vector_type(4)));
typedef float    f32x4 __attribute__((ext_vector_type(4)));
typedef unsigned int u32;
#define AS1 __attribute__((address_space(1)))
#define AS3 __attribute__((address_space(3)))

// K/V tile = 64x64 f16 = 8192 B stored as the EXACT swizzled LDS image
// (row r * 128 B, 16B-group g at g ^ (r&7)) so attention can DMA verbatim
// with global_load_lds and all ds_read_b128 fragments stay conflict-free.
// Failure ledger: R7 direct-global frags = latency-bound (131us, reverted).
// R8/R9 both FAILED correctness; common delta = s_setprio around MFMAs ->
// setprio is permanently parked for this kernel. R10 = exact R0 attn text
// (108.4us validated) + ONE variable: batched preprocess (1536->384 blocks).
#define TILE_B  8192
#define KT_BYTES ((size_t)NB*NH*NCH*TILE_B)   // 12,582,912 (K tiles)
#define WS_FULL  (2*KT_BYTES)                 // 25,165,824 (K+V tiles)

static __device__ __forceinline__ int dec_xcd(int id, int& b, int& h, int& q0) {
    // XCD swizzle (R6-validated): all 16 q-tiles of one (b,h) share id%8
    const int xcd = id & 7;
    const int qt  = (id >> 3) & 15;
    const int grp = id >> 7;          // 0..5
    const int bh  = grp * 8 + xcd;    // 0..47
    b = bh / NH; h = bh - b * NH; q0 = qt * TQ;
    return bh;
}

// ---------------------------------------------------------------------------
// Preprocess: LayerNorm K into swizzled f16 tiles (always); V transposed
// tiles too when writeV!=0.  R10: grid (8,12,4) = 384 blocks, each handling
// 4 consecutive mc-chunks; per-chunk body is the R0-validated text verbatim
// inside the sub-loop. Targets the ~104us residual (launch/tail overhead of
// 1536 tiny 48KB blocks).
// ---------------------------------------------------------------------------
__global__ __launch_bounds__(256, 4)
void preprocess_kernel(const float* __restrict__ QKV,
                       const float* __restrict__ k_scale,
                       const float* __restrict__ k_bias,
                       unsigned char* __restrict__ ws, int writeV)
{
    const int tid = threadIdx.x;
    const int L   = tid & 63;
    const int wv  = tid >> 6;
    const int r4  = L >> 2;
    const int c4  = L & 3;
    const int h = blockIdx.y, b = blockIdx.z;

    const float4* QKV4 = (const float4*)QKV;
    const int row = wv*16 + r4;

    for (int sub = 0; sub < 4; ++sub) {
        const int mc = blockIdx.x * 4 + sub;

        unsigned char* Kt = ws + (size_t)((b*NH + h)*NCH + mc) * TILE_B;
        const size_t base4 = (size_t)(b*SEQ + mc*64 + row) * 576 + h*16 + c4*4;

        {   // K: LN -> swizzled tile image
            float4 x[4];
            #pragma unroll
            for (int i = 0; i < 4; ++i) x[i] = QKV4[base4 + 192 + i];
            float s = 0.f, s2 = 0.f;
            #pragma unroll
            for (int i = 0; i < 4; ++i) {
                s  += x[i].x + x[i].y + x[i].z + x[i].w;
                s2 += x[i].x*x[i].x + x[i].y*x[i].y + x[i].z*x[i].z + x[i].w*x[i].w;
            }
            s  += __shfl_xor(s, 1);  s  += __shfl_xor(s, 2);
            s2 += __shfl_xor(s2, 1); s2 += __shfl_xor(s2, 2);
            float mu = s * 0.015625f;
            float rstd = rsqrtf(s2 * 0.015625f - mu*mu + 1e-6f);
            float nb0 = -mu * rstd;
            half8 h0, h1;
            #pragma unroll
            for (int i = 0; i < 4; ++i) {
                float4 sc = ((const float4*)k_scale)[c4*4 + i];
                float4 bi = ((const float4*)k_bias)[c4*4 + i];
                float e0 = fmaf(x[i].x, rstd, nb0) * sc.x + bi.x;
                float e1 = fmaf(x[i].y, rstd, nb0) * sc.y + bi.y;
                float e2 = fmaf(x[i].z, rstd, nb0) * sc.z + bi.z;
                float e3 = fmaf(x[i].w, rstd, nb0) * sc.w + bi.w;
                if (i < 2) { h0[i*4+0]=(_Float16)e0; h0[i*4+1]=(_Float16)e1; h0[i*4+2]=(_Float16)e2; h0[i*4+3]=(_Float16)e3; }
                else { int j=(i-2)*4; h1[j+0]=(_Float16)e0; h1[j+1]=(_Float16)e1; h1[j+2]=(_Float16)e2; h1[j+3]=(_Float16)e3; }
            }
            *(half8*)(Kt + row*128 + (((2*c4+0) ^ (row & 7)) * 16)) = h0;
            *(half8*)(Kt + row*128 + (((2*c4+1) ^ (row & 7)) * 16)) = h1;
        }

        if (writeV) {   // V: transpose -> swizzled tile (lane = d)
            unsigned char* Vt = ws + KT_BYTES + (size_t)((b*NH + h)*NCH + mc) * TILE_B;
            const float* gv = QKV + (size_t)(b*SEQ + mc*64 + wv*16)*CIN + 1536 + h*64 + L;
            float vvp[16];
            #pragma unroll
            for (int j = 0; j < 16; ++j) vvp[j] = gv[(size_t)j * CIN];
            half8 a0, a1;
            #pragma unroll
            for (int j = 0; j < 8; ++j) { a0[j] = (_Float16)vvp[j]; a1[j] = (_Float16)vvp[j+8]; }
            *(half8*)(Vt + L*128 + (((2*wv+0) ^ (L & 7)) * 16)) = a0;
            *(half8*)(Vt + L*128 + (((2*wv+1) ^ (L & 7)) * 16)) = a1;
        }
    }
}

// Shared Q-prologue + fragment pickup (R0-validated text), emitted inline.
#define Q_PROLOGUE(QTBASE)                                                        \
    const float SC = 0.125f * 1.44269504088896340736f;                            \
    _Pragma("unroll")                                                             \
    for (int g = 0; g < 2; ++g) {                                                 \
        const int row = wv*32 + g*16 + r4;                                        \
        const size_t base4 = (size_t)(b*SEQ + q0 + row) * 576 + h*16 + c4*4;      \
        float4 x[4];                                                              \
        _Pragma("unroll")                                                         \
        for (int i = 0; i < 4; ++i) x[i] = QKV4[base4 + i];                       \
        float s = 0.f, s2 = 0.f;                                                  \
        _Pragma("unroll")                                                         \
        for (int i = 0; i < 4; ++i) {                                             \
            s  += x[i].x + x[i].y + x[i].z + x[i].w;                              \
            s2 += x[i].x*x[i].x + x[i].y*x[i].y + x[i].z*x[i].z + x[i].w*x[i].w;  \
        }                                                                         \
        s  += __shfl_xor(s, 1);  s  += __shfl_xor(s, 2);                          \
        s2 += __shfl_xor(s2, 1); s2 += __shfl_xor(s2, 2);                         \
        float mu = s * 0.015625f;                                                 \
        float rstd = rsqrtf(s2 * 0.015625f - mu*mu + 1e-6f);                      \
        float nb0 = -mu * rstd;                                                   \
        half8 h0, h1;                                                             \
        _Pragma("unroll")                                                         \
        for (int i = 0; i < 4; ++i) {                                             \
            float4 sc = ((const float4*)q_scale)[c4*4 + i];                       \
            float4 bi = ((const float4*)q_bias)[c4*4 + i];                        \
            float e0 = (fmaf(x[i].x, rstd, nb0) * sc.x + bi.x) * SC;              \
            float e1 = (fmaf(x[i].y, rstd, nb0) * sc.y + bi.y) * SC;              \
            float e2 = (fmaf(x[i].z, rstd, nb0) * sc.z + bi.z) * SC;              \
            float e3 = (fmaf(x[i].w, rstd, nb0) * sc.w + bi.w) * SC;              \
            if (i < 2) { h0[i*4+0]=(_Float16)e0; h0[i*4+1]=(_Float16)e1; h0[i*4+2]=(_Float16)e2; h0[i*4+3]=(_Float16)e3; } \
            else { int j=(i-2)*4; h1[j+0]=(_Float16)e0; h1[j+1]=(_Float16)e1; h1[j+2]=(_Float16)e2; h1[j+3]=(_Float16)e3; } \
        }                                                                         \
        *(half8*)((QTBASE) + row*128 + (((2*c4+0) ^ (r4 & 7)) * 16)) = h0;        \
        *(half8*)((QTBASE) + row*128 + (((2*c4+1) ^ (r4 & 7)) * 16)) = h1;        \
    }                                                                             \
    half8 qf[2][2];                                                               \
    _Pragma("unroll")                                                             \
    for (int s = 0; s < 2; ++s) {                                                 \
        const unsigned char* qrow = (QTBASE) + (wv*32 + s*16 + n16)*128;          \
        _Pragma("unroll")                                                         \
        for (int ks = 0; ks < 2; ++ks)                                            \
            qf[s][ks] = *(const half8*)(qrow + (((quad + 4*ks) ^ sw) * 16));      \
    }

// Compute body for one chunk given Ka/Vt base pointers.
// R10: byte-identical to the R0 text validated at 108.4us (no setprio, no
// av-hoist, original ^n16 P layout).
#define CHUNK_COMPUTE(KAB, VTB)                                                   \
    {                                                                             \
        f32x4 sacc[2][4] = {};                                                    \
        _Pragma("unroll")                                                         \
        for (int ks = 0; ks < 2; ++ks) {                                          \
            half8 ak[4];                                                          \
            _Pragma("unroll")                                                     \
            for (int mt = 0; mt < 4; ++mt)                                        \
                ak[mt] = *(const half8*)((KAB) + (16*mt + n16)*128 + (((quad + 4*ks) ^ sw) * 16)); \
            _Pragma("unroll")                                                     \
            for (int s = 0; s < 2; ++s)                                           \
                _Pragma("unroll")                                                 \
                for (int mt = 0; mt < 4; ++mt)                                    \
                    sacc[s][mt] = __builtin_amdgcn_mfma_f32_16x16x32_f16(ak[mt], qf[s][ks], sacc[s][mt], 0, 0, 0); \
        }                                                                         \
        _Pragma("unroll")                                                         \
        for (int s = 0; s < 2; ++s) {                                             \
            float ls = 0.f;                                                       \
            _Pragma("unroll")                                                     \
            for (int mt = 0; mt < 4; ++mt) {                                      \
                float p0 = __builtin_exp2f(sacc[s][mt][0]);                       \
                float p1 = __builtin_exp2f(sacc[s][mt][1]);                       \
                float p2 = __builtin_exp2f(sacc[s][mt][2]);                       \
                float p3 = __builtin_exp2f(sacc[s][mt][3]);                       \
                ls += (p0 + p1) + (p2 + p3);                                      \
                half4 hp; hp[0]=(_Float16)p0; hp[1]=(_Float16)p1; hp[2]=(_Float16)p2; hp[3]=(_Float16)p3; \
                *(half4*)(Pw + s*2048 + n16*128 + (((4*mt + quad) ^ n16) * 8)) = hp; \
            }                                                                     \
            ls += __shfl_xor(ls, 16);                                             \
            ls += __shfl_xor(ls, 32);                                             \
            lsum[s] += ls;                                                        \
        }                                                                         \
        _Pragma("unroll")                                                         \
        for (int ks = 0; ks < 2; ++ks) {                                          \
            half8 av[4];                                                          \
            _Pragma("unroll")                                                     \
            for (int mt = 0; mt < 4; ++mt)                                        \
                av[mt] = *(const half8*)((VTB) + (16*mt + n16)*128 + (((quad + 4*ks) ^ sw) * 16)); \
            _Pragma("unroll")                                                     \
            for (int s = 0; s < 2; ++s) {                                         \
                half4 b0 = *(const half4*)(Pw + s*2048 + n16*128 + (((8*ks + 2*quad + 0) ^ n16) * 8)); \
                half4 b1 = *(const half4*)(Pw + s*2048 + n16*128 + (((8*ks + 2*quad + 1) ^ n16) * 8)); \
                half8 bp;                                                         \
                _Pragma("unroll")                                                 \
                for (int j = 0; j < 4; ++j) { bp[j] = b0[j]; bp[4+j] = b1[j]; }   \
                _Pragma("unroll")                                                 \
                for (int mt = 0; mt < 4; ++mt)                                    \
                    oacc[s][mt] = __builtin_amdgcn_mfma_f32_16x16x32_f16(av[mt], bp, oacc[s][mt], 0, 0, 0); \
            }                                                                     \
        }                                                                         \
    }

#define EPILOGUE()                                                                \
    {                                                                             \
        float4* out4 = (float4*)out;                                              \
        _Pragma("unroll")                                                         \
        for (int s = 0; s < 2; ++s) {                                             \
            float inv = 1.0f / lsum[s];                                           \
            size_t rowb = ((size_t)(b*NH + h)*SEQ + q0 + wv*32 + s*16 + n16) * 16;\
            _Pragma("unroll")                                                     \
            for (int mt = 0; mt < 4; ++mt)                                        \
                out4[rowb + mt*4 + quad] = make_float4(oacc[s][mt][0]*inv, oacc[s][mt][1]*inv, oacc[s][mt][2]*inv, oacc[s][mt][3]*inv); \
        }                                                                         \
    }

#define COMMON_IDS()                                                              \
    const int tid  = threadIdx.x;                                                 \
    const int L    = tid & 63;                                                    \
    const int wv   = tid >> 6;                                                    \
    const int n16  = L & 15;                                                      \
    const int quad = L >> 4;                                                      \
    const int sw   = n16 & 7;                                                     \
    const int r4   = L >> 2;                                                      \
    const int c4   = L & 3;                                                       \
    int b, h, q0; dec_xcd(blockIdx.x, b, h, q0);                                  \
    const float4* QKV4 = (const float4*)QKV;

// ---------------------------------------------------------------------------
// Tier (a): both K and V tiles DMA'd, double-buffered, 1 barrier/chunk.
// (Exact R0 shell + body - validated at 108.4 us.)
// ---------------------------------------------------------------------------
__global__ __launch_bounds__(256, 3)
void attn_full(const float* __restrict__ QKV,
               const float* __restrict__ q_scale,
               const float* __restrict__ q_bias,
               const unsigned char* __restrict__ ws,
               float* __restrict__ out)
{
    __shared__ __align__(16) unsigned char sm[49152]; // 2x(Ka8K|Vt8K) + Qt/P 16K
    COMMON_IDS()
    unsigned char* Qt = sm + 32768;
    unsigned char* Pw = Qt + wv*4096;

    const unsigned char* Ktiles = ws + (size_t)((b*NH + h)*NCH) * TILE_B;
    const unsigned char* Vtiles = ws + KT_BYTES + (size_t)((b*NH + h)*NCH) * TILE_B;

    #define ISSUE_KV(MC, P)                                                       \
    {                                                                             \
        const unsigned char* kt_ = Ktiles + (size_t)(MC) * TILE_B;                \
        const unsigned char* vt_ = Vtiles + (size_t)(MC) * TILE_B;                \
        unsigned char* lk_ = sm + (P)*16384;                                      \
        unsigned char* lv_ = lk_ + 8192;                                          \
        _Pragma("unroll")                                                         \
        for (int t_ = 0; t_ < 2; ++t_) {                                          \
            int seg_ = wv*2 + t_;                                                 \
            __builtin_amdgcn_global_load_lds((const AS1 u32*)(kt_ + seg_*1024 + L*16), \
                                             (AS3 u32*)(lk_ + seg_*1024), 16, 0, 0);   \
            __builtin_amdgcn_global_load_lds((const AS1 u32*)(vt_ + seg_*1024 + L*16), \
                                             (AS3 u32*)(lv_ + seg_*1024), 16, 0, 0);   \
        }                                                                         \
    }

    ISSUE_KV(0, 0)
    Q_PROLOGUE(Qt)

    f32x4 oacc[2][4] = {};
    float lsum[2] = {0.f, 0.f};

    for (int mc = 0; mc < NCH; ++mc) {
        const int p = mc & 1;
        __syncthreads();                       // DMA(mc) landed; buf p^1 reads done
        if (mc + 1 < NCH) ISSUE_KV(mc + 1, p ^ 1)
        const unsigned char* Ka = sm + p*16384;
        const unsigned char* Vt = Ka + 8192;
        CHUNK_COMPUTE(Ka, Vt)
    }
    EPILOGUE()
    #undef ISSUE_KV
}

// ---------------------------------------------------------------------------
// Tier (b): K tiles DMA'd (dbuf), V staged in-kernel (R6 path), 2 barriers.
// ---------------------------------------------------------------------------
__global__ __launch_bounds__(256, 3)
void attn_ktile(const float* __restrict__ QKV,
                const float* __restrict__ q_scale,
                const float* __restrict__ q_bias,
                const unsigned char* __restrict__ ws,
                float* __restrict__ out)
{
    __shared__ __align__(16) unsigned char sm[40960]; // Kbuf0 8K|Kbuf1 8K|Vt 8K|Qt/P 16K
    COMMON_IDS()
    unsigned char* Vt = sm + 16384;
    unsigned char* Qt = sm + 24576;
    unsigned char* Pw = Qt + wv*4096;

    const unsigned char* Ktiles = ws + (size_t)((b*NH + h)*NCH) * TILE_B;

    #define ISSUE_K(MC, P)                                                        \
    {                                                                             \
        const unsigned char* kt_ = Ktiles + (size_t)(MC) * TILE_B;                \
        unsigned char* lk_ = sm + (P)*8192;                                       \
        _Pragma("unroll")                                                         \
        for (int t_ = 0; t_ < 2; ++t_) {                                          \
            int seg_ = wv*2 + t_;                                                 \
            __builtin_amdgcn_global_load_lds((const AS1 u32*)(kt_ + seg_*1024 + L*16), \
                                             (AS3 u32*)(lk_ + seg_*1024), 16, 0, 0);   \
        }                                                                         \
    }
    float vv[16];
    #define PREFETCH_V(MC)                                                        \
    {                                                                             \
        const float* gv = QKV + (size_t)(b*SEQ + (MC)*64 + wv*16) * CIN + 1536 + h*64 + L; \
        _Pragma("unroll")                                                         \
        for (int j = 0; j < 16; ++j) vv[j] = gv[(size_t)j * CIN];                 \
    }
    #define STAGE_V()                                                             \
    {                                                                             \
        half8 a0, a1;                                                             \
        _Pragma("unroll")                                                         \
        for (int j = 0; j < 8; ++j) { a0[j] = (_Float16)vv[j]; a1[j] = (_Float16)vv[j+8]; } \
        *(half8*)(Vt + L*128 + (((2*wv+0) ^ (L & 7)) * 16)) = a0;                 \
        *(half8*)(Vt + L*128 + (((2*wv+1) ^ (L & 7)) * 16)) = a1;                 \
    }

    PREFETCH_V(0)
    ISSUE_K(0, 0)
    Q_PROLOGUE(Qt)

    f32x4 oacc[2][4] = {};
    float lsum[2] = {0.f, 0.f};

    for (int mc = 0; mc < NCH; ++mc) {
        const int p = mc & 1;
        __syncthreads();                    // K-DMA(mc) landed; prev Vt reads done
        STAGE_V()
        __syncthreads();                    // Vt visible
        if (mc + 1 < NCH) { ISSUE_K(mc + 1, p ^ 1) PREFETCH_V(mc + 1) }
        const unsigned char* Ka = sm + p*8192;
        CHUNK_COMPUTE(Ka, Vt)
    }
    EPILOGUE()
    #undef ISSUE_K
    #undef PREFETCH_V
    #undef STAGE_V
}

// ---------------------------------------------------------------------------
// Tier (c) fallback: exact R6 fused kernel (validated).
// ---------------------------------------------------------------------------
__global__ __launch_bounds__(256, 3)
void fused_fallback(const float* __restrict__ QKV,
                    const float* __restrict__ q_scale,
                    const float* __restrict__ q_bias,
                    const float* __restrict__ k_scale,
                    const float* __restrict__ k_bias,
                    float* __restrict__ out)
{
    __shared__ __align__(16) unsigned char sm[32768];
    COMMON_IDS()
    unsigned char* Ka = sm;
    unsigned char* Vt = sm + 8192;
    unsigned char* Qt = sm + 16384;
    unsigned char* Pw = Qt + wv*4096;

    float4 ksr[4], kbr[4];
    #pragma unroll
    for (int i = 0; i < 4; ++i) {
        ksr[i] = ((const float4*)k_scale)[c4 * 4 + i];
        kbr[i] = ((const float4*)k_bias)[c4 * 4 + i];
    }
    float4 kx[4];
    float  vv[16];
    #define PREFETCH(MC)                                                          \
    {                                                                             \
        const size_t kb4 = (size_t)(b*SEQ + (MC)*64 + wv*16 + r4) * 576 + 192 + h*16 + c4*4; \
        _Pragma("unroll")                                                         \
        for (int i = 0; i < 4; ++i) kx[i] = QKV4[kb4 + i];                        \
        const float* gv = QKV + (size_t)(b*SEQ + (MC)*64 + wv*16) * CIN + 1536 + h*64 + L; \
        _Pragma("unroll")                                                         \
        for (int j = 0; j < 16; ++j) vv[j] = gv[(size_t)j * CIN];                 \
    }
    #define STAGE_KV()                                                            \
    {                                                                             \
        const int row = wv*16 + r4;                                               \
        float s = 0.f, s2 = 0.f;                                                  \
        _Pragma("unroll")                                                         \
        for (int i = 0; i < 4; ++i) {                                             \
            s  += kx[i].x + kx[i].y + kx[i].z + kx[i].w;                          \
            s2 += kx[i].x*kx[i].x + kx[i].y*kx[i].y + kx[i].z*kx[i].z + kx[i].w*kx[i].w; \
        }                                                                         \
        s  += __shfl_xor(s, 1);  s  += __shfl_xor(s, 2);                          \
        s2 += __shfl_xor(s2, 1); s2 += __shfl_xor(s2, 2);                         \
        float mu = s * 0.015625f;                                                 \
        float rstd = rsqrtf(s2 * 0.015625f - mu*mu + 1e-6f);                      \
        float nb0 = -mu * rstd;                                                   \
        half8 h0, h1;                                                             \
        _Pragma("unroll")                                                         \
        for (int i = 0; i < 4; ++i) {                                             \
            float e0 = fmaf(kx[i].x, rstd, nb0) * ksr[i].x + kbr[i].x;            \
            float e1 = fmaf(kx[i].y, rstd, nb0) * ksr[i].y + kbr[i].y;            \
            float e2 = fmaf(kx[i].z, rstd, nb0) * ksr[i].z + kbr[i].z;            \
            float e3 = fmaf(kx[i].w, rstd, nb0) * ksr[i].w + kbr[i].w;            \
            if (i < 2) { h0[i*4+0]=(_Float16)e0; h0[i*4+1]=(_Float16)e1; h0[i*4+2]=(_Float16)e2; h0[i*4+3]=(_Float16)e3; } \
            else { int j=(i-2)*4; h1[j+0]=(_Float16)e0; h1[j+1]=(_Float16)e1; h1[j+2]=(_Float16)e2; h1[j+3]=(_Float16)e3; } \
        }                                                                         \
        *(half8*)(Ka + row*128 + (((2*c4+0) ^ (row & 7)) * 16)) = h0;             \
        *(half8*)(Ka + row*128 + (((2*c4+1) ^ (row & 7)) * 16)) = h1;             \
        half8 a0, a1;                                                             \
        _Pragma("unroll")                                                         \
        for (int j = 0; j < 8; ++j) { a0[j] = (_Float16)vv[j]; a1[j] = (_Float16)vv[j+8]; } \
        *(half8*)(Vt + L*128 + (((2*wv+0) ^ (L & 7)) * 16)) = a0;                 \
        *(half8*)(Vt + L*128 + (((2*wv+1) ^ (L & 7)) * 16)) = a1;                 \
    }

    PREFETCH(0)
    Q_PROLOGUE(Qt)

    f32x4 oacc[2][4] = {};
    float lsum[2] = {0.f, 0.f};

    for (int mc = 0; mc < NCH; ++mc) {
        __syncthreads();
        STAGE_KV()
        __syncthreads();
        if (mc + 1 < NCH) PREFETCH(mc + 1)
        CHUNK_COMPUTE(Ka, Vt)
    }
    EPILOGUE()
    #undef PREFETCH
    #undef STAGE_KV
}

extern "C" void kernel_launch(void* const* d_in, const int* in_sizes, int n_in,
                              void* d_out, int out_size, void* d_ws, size_t ws_size,
                              hipStream_t stream) {
    const float* QKV     = (const float*)d_in[0];
    const float* q_scale = (const float*)d_in[1];
    const float* q_bias  = (const float*)d_in[2];
    const float* k_scale = (const float*)d_in[3];
    const float* k_bias  = (const float*)d_in[4];
    float* out = (float*)d_out;
    unsigned char* ws = (unsigned char*)d_ws;

    const dim3 agrid(NB * NH * (SEQ / TQ));   // 768 flat, XCD-decoded inside
    if (ws_size >= WS_FULL) {
        preprocess_kernel<<<dim3(NCH/4, NH, NB), 256, 0, stream>>>(QKV, k_scale, k_bias, ws, 1);
        attn_full<<<agrid, 256, 0, stream>>>(QKV, q_scale, q_bias, ws, out);
    } else if (ws_size >= KT_BYTES) {
        preprocess_kernel<<<dim3(NCH/4, NH, NB), 256, 0, stream>>>(QKV, k_scale, k_bias, ws, 0);
        attn_ktile<<<agrid, 256, 0, stream>>>(QKV, q_scale, q_bias, ws, out);
    } else {
        fused_fallback<<<agrid, 256, 0, stream>>>(QKV, q_scale, q_bias, k_scale, k_bias, out);
    }
}

// Round 7
// 208.721 us; speedup vs baseline: 1.1175x; 1.0403x over previous
//
#include <hip/hip_runtime.h>
#include <math.h>

// Problem constants
#define NB   4
#define SEQ  2048
#define NH   12
#define CIN  2304      // 3*768 floats per token
#define TM   64        // kv rows per chunk
#define NCH  (SEQ/TM)  // 32 chunks
#define TQ   128       // q rows per block (4 waves x 32 q)

typedef _Float16 half8 __attribute__((ext_vector_type(8)));
typedef _Float16 half4 __attribute__((ext_vector_type(4)));
typedef float    f32x4 __attribute__((ext_vector_type(4)));
typedef unsigned int u32;
#define AS1 __attribute__((address_space(1)))
#define AS3 __attribute__((address_space(3)))

// K/V tile = 64x64 f16 = 8192 B stored as the EXACT swizzled LDS image
// (row r * 128 B, 16B-group g at g ^ (r&7)) so attention can DMA verbatim
// with global_load_lds and all ds_read_b128 fragments stay conflict-free.
// Session ledger:
//   R7  direct-global frags: latency-bound, 131us -> reverted to DMA dbuf.
//   R8/R9  setprio-bearing kernels failed correctness -> setprio parked.
//   R10 preprocess batching: neutral (residual is not launch overhead).
//   R11 8-wave restructure: failed correctness (absmax 0.08) -> parked.
//   R12 (this): R0 shell + R1-validated CHUNK_COMPUTE (av-hoist, no setprio).
#define TILE_B  8192
#define KT_BYTES ((size_t)NB*NH*NCH*TILE_B)   // 12,582,912 (K tiles)
#define WS_FULL  (2*KT_BYTES)                 // 25,165,824 (K+V tiles)

static __device__ __forceinline__ int dec_xcd(int id, int& b, int& h, int& q0) {
    // XCD swizzle (R6-validated): all 16 q-tiles of one (b,h) share id%8
    const int xcd = id & 7;
    const int qt  = (id >> 3) & 15;
    const int grp = id >> 7;          // 0..5
    const int bh  = grp * 8 + xcd;    // 0..47
    b = bh / NH; h = bh - b * NH; q0 = qt * TQ;
    return bh;
}

// ---------------------------------------------------------------------------
// Preprocess: exact R0-validated text (grid (32,12,4), per-chunk blocks).
// ---------------------------------------------------------------------------
__global__ __launch_bounds__(256, 4)
void preprocess_kernel(const float* __restrict__ QKV,
                       const float* __restrict__ k_scale,
                       const float* __restrict__ k_bias,
                       unsigned char* __restrict__ ws, int writeV)
{
    const int tid = threadIdx.x;
    const int L   = tid & 63;
    const int wv  = tid >> 6;
    const int r4  = L >> 2;
    const int c4  = L & 3;
    const int mc  = blockIdx.x, h = blockIdx.y, b = blockIdx.z;

    unsigned char* Kt = ws + (size_t)((b*NH + h)*NCH + mc) * TILE_B;

    const float4* QKV4 = (const float4*)QKV;
    const int row = wv*16 + r4;
    const size_t base4 = (size_t)(b*SEQ + mc*64 + row) * 576 + h*16 + c4*4;

    {   // K: LN -> swizzled tile image
        float4 x[4];
        #pragma unroll
        for (int i = 0; i < 4; ++i) x[i] = QKV4[base4 + 192 + i];
        float s = 0.f, s2 = 0.f;
        #pragma unroll
        for (int i = 0; i < 4; ++i) {
            s  += x[i].x + x[i].y + x[i].z + x[i].w;
            s2 += x[i].x*x[i].x + x[i].y*x[i].y + x[i].z*x[i].z + x[i].w*x[i].w;
        }
        s  += __shfl_xor(s, 1);  s  += __shfl_xor(s, 2);
        s2 += __shfl_xor(s2, 1); s2 += __shfl_xor(s2, 2);
        float mu = s * 0.015625f;
        float rstd = rsqrtf(s2 * 0.015625f - mu*mu + 1e-6f);
        float nb0 = -mu * rstd;
        half8 h0, h1;
        #pragma unroll
        for (int i = 0; i < 4; ++i) {
            float4 sc = ((const float4*)k_scale)[c4*4 + i];
            float4 bi = ((const float4*)k_bias)[c4*4 + i];
            float e0 = fmaf(x[i].x, rstd, nb0) * sc.x + bi.x;
            float e1 = fmaf(x[i].y, rstd, nb0) * sc.y + bi.y;
            float e2 = fmaf(x[i].z, rstd, nb0) * sc.z + bi.z;
            float e3 = fmaf(x[i].w, rstd, nb0) * sc.w + bi.w;
            if (i < 2) { h0[i*4+0]=(_Float16)e0; h0[i*4+1]=(_Float16)e1; h0[i*4+2]=(_Float16)e2; h0[i*4+3]=(_Float16)e3; }
            else { int j=(i-2)*4; h1[j+0]=(_Float16)e0; h1[j+1]=(_Float16)e1; h1[j+2]=(_Float16)e2; h1[j+3]=(_Float16)e3; }
        }
        *(half8*)(Kt + row*128 + (((2*c4+0) ^ (row & 7)) * 16)) = h0;
        *(half8*)(Kt + row*128 + (((2*c4+1) ^ (row & 7)) * 16)) = h1;
    }

    if (writeV) {   // V: transpose -> swizzled tile (lane = d)
        unsigned char* Vt = ws + KT_BYTES + (size_t)((b*NH + h)*NCH + mc) * TILE_B;
        const float* gv = QKV + (size_t)(b*SEQ + mc*64 + wv*16)*CIN + 1536 + h*64 + L;
        float vvp[16];
        #pragma unroll
        for (int j = 0; j < 16; ++j) vvp[j] = gv[(size_t)j * CIN];
        half8 a0, a1;
        #pragma unroll
        for (int j = 0; j < 8; ++j) { a0[j] = (_Float16)vvp[j]; a1[j] = (_Float16)vvp[j+8]; }
        *(half8*)(Vt + L*128 + (((2*wv+0) ^ (L & 7)) * 16)) = a0;
        *(half8*)(Vt + L*128 + (((2*wv+1) ^ (L & 7)) * 16)) = a1;
    }
}

// Shared Q-prologue + fragment pickup (R0-validated text), emitted inline.
#define Q_PROLOGUE(QTBASE)                                                        \
    const float SC = 0.125f * 1.44269504088896340736f;                            \
    _Pragma("unroll")                                                             \
    for (int g = 0; g < 2; ++g) {                                                 \
        const int row = wv*32 + g*16 + r4;                                        \
        const size_t base4 = (size_t)(b*SEQ + q0 + row) * 576 + h*16 + c4*4;      \
        float4 x[4];                                                              \
        _Pragma("unroll")                                                         \
        for (int i = 0; i < 4; ++i) x[i] = QKV4[base4 + i];                       \
        float s = 0.f, s2 = 0.f;                                                  \
        _Pragma("unroll")                                                         \
        for (int i = 0; i < 4; ++i) {                                             \
            s  += x[i].x + x[i].y + x[i].z + x[i].w;                              \
            s2 += x[i].x*x[i].x + x[i].y*x[i].y + x[i].z*x[i].z + x[i].w*x[i].w;  \
        }                                                                         \
        s  += __shfl_xor(s, 1);  s  += __shfl_xor(s, 2);                          \
        s2 += __shfl_xor(s2, 1); s2 += __shfl_xor(s2, 2);                         \
        float mu = s * 0.015625f;                                                 \
        float rstd = rsqrtf(s2 * 0.015625f - mu*mu + 1e-6f);                      \
        float nb0 = -mu * rstd;                                                   \
        half8 h0, h1;                                                             \
        _Pragma("unroll")                                                         \
        for (int i = 0; i < 4; ++i) {                                             \
            float4 sc = ((const float4*)q_scale)[c4*4 + i];                       \
            float4 bi = ((const float4*)q_bias)[c4*4 + i];                        \
            float e0 = (fmaf(x[i].x, rstd, nb0) * sc.x + bi.x) * SC;              \
            float e1 = (fmaf(x[i].y, rstd, nb0) * sc.y + bi.y) * SC;              \
            float e2 = (fmaf(x[i].z, rstd, nb0) * sc.z + bi.z) * SC;              \
            float e3 = (fmaf(x[i].w, rstd, nb0) * sc.w + bi.w) * SC;              \
            if (i < 2) { h0[i*4+0]=(_Float16)e0; h0[i*4+1]=(_Float16)e1; h0[i*4+2]=(_Float16)e2; h0[i*4+3]=(_Float16)e3; } \
            else { int j=(i-2)*4; h1[j+0]=(_Float16)e0; h1[j+1]=(_Float16)e1; h1[j+2]=(_Float16)e2; h1[j+3]=(_Float16)e3; } \
        }                                                                         \
        *(half8*)((QTBASE) + row*128 + (((2*c4+0) ^ (r4 & 7)) * 16)) = h0;        \
        *(half8*)((QTBASE) + row*128 + (((2*c4+1) ^ (r4 & 7)) * 16)) = h1;        \
    }                                                                             \
    half8 qf[2][2];                                                               \
    _Pragma("unroll")                                                             \
    for (int s = 0; s < 2; ++s) {                                                 \
        const unsigned char* qrow = (QTBASE) + (wv*32 + s*16 + n16)*128;          \
        _Pragma("unroll")                                                         \
        for (int ks = 0; ks < 2; ++ks)                                            \
            qf[s][ks] = *(const half8*)(qrow + (((quad + 4*ks) ^ sw) * 16));      \
    }

// Compute body for one chunk given Ka/Vt base pointers.
// R12: byte-identical to the R1-validated macro (av[2][4] hoist before the
// softmax so V-frag ds_read latency hides under exp2; identical bytes read
// within the same barrier epoch; original ^n16 P layout; no setprio).
#define CHUNK_COMPUTE(KAB, VTB)                                                   \
    {                                                                             \
        f32x4 sacc[2][4] = {};                                                    \
        _Pragma("unroll")                                                         \
        for (int ks = 0; ks < 2; ++ks) {                                          \
            half8 ak[4];                                                          \
            _Pragma("unroll")                                                     \
            for (int mt = 0; mt < 4; ++mt)                                        \
                ak[mt] = *(const half8*)((KAB) + (16*mt + n16)*128 + (((quad + 4*ks) ^ sw) * 16)); \
            _Pragma("unroll")                                                     \
            for (int s = 0; s < 2; ++s)                                           \
                _Pragma("unroll")                                                 \
                for (int mt = 0; mt < 4; ++mt)                                    \
                    sacc[s][mt] = __builtin_amdgcn_mfma_f32_16x16x32_f16(ak[mt], qf[s][ks], sacc[s][mt], 0, 0, 0); \
        }                                                                         \
        half8 av[2][4];                                                           \
        _Pragma("unroll")                                                         \
        for (int ks = 0; ks < 2; ++ks)                                            \
            _Pragma("unroll")                                                     \
            for (int mt = 0; mt < 4; ++mt)                                        \
                av[ks][mt] = *(const half8*)((VTB) + (16*mt + n16)*128 + (((quad + 4*ks) ^ sw) * 16)); \
        _Pragma("unroll")                                                         \
        for (int s = 0; s < 2; ++s) {                                             \
            float ls = 0.f;                                                       \
            _Pragma("unroll")                                                     \
            for (int mt = 0; mt < 4; ++mt) {                                      \
                float p0 = __builtin_exp2f(sacc[s][mt][0]);                       \
                float p1 = __builtin_exp2f(sacc[s][mt][1]);                       \
                float p2 = __builtin_exp2f(sacc[s][mt][2]);                       \
                float p3 = __builtin_exp2f(sacc[s][mt][3]);                       \
                ls += (p0 + p1) + (p2 + p3);                                      \
                half4 hp; hp[0]=(_Float16)p0; hp[1]=(_Float16)p1; hp[2]=(_Float16)p2; hp[3]=(_Float16)p3; \
                *(half4*)(Pw + s*2048 + n16*128 + (((4*mt + quad) ^ n16) * 8)) = hp; \
            }                                                                     \
            ls += __shfl_xor(ls, 16);                                             \
            ls += __shfl_xor(ls, 32);                                             \
            lsum[s] += ls;                                                        \
        }                                                                         \
        _Pragma("unroll")                                                         \
        for (int ks = 0; ks < 2; ++ks) {                                          \
            _Pragma("unroll")                                                     \
            for (int s = 0; s < 2; ++s) {                                         \
                half4 b0 = *(const half4*)(Pw + s*2048 + n16*128 + (((8*ks + 2*quad + 0) ^ n16) * 8)); \
                half4 b1 = *(const half4*)(Pw + s*2048 + n16*128 + (((8*ks + 2*quad + 1) ^ n16) * 8)); \
                half8 bp;                                                         \
                _Pragma("unroll")                                                 \
                for (int j = 0; j < 4; ++j) { bp[j] = b0[j]; bp[4+j] = b1[j]; }   \
                _Pragma("unroll")                                                 \
                for (int mt = 0; mt < 4; ++mt)                                    \
                    oacc[s][mt] = __builtin_amdgcn_mfma_f32_16x16x32_f16(av[ks][mt], bp, oacc[s][mt], 0, 0, 0); \
            }                                                                     \
        }                                                                         \
    }

#define EPILOGUE()                                                                \
    {                                                                             \
        float4* out4 = (float4*)out;                                              \
        _Pragma("unroll")                                                         \
        for (int s = 0; s < 2; ++s) {                                             \
            float inv = 1.0f / lsum[s];                                           \
            size_t rowb = ((size_t)(b*NH + h)*SEQ + q0 + wv*32 + s*16 + n16) * 16;\
            _Pragma("unroll")                                                     \
            for (int mt = 0; mt < 4; ++mt)                                        \
                out4[rowb + mt*4 + quad] = make_float4(oacc[s][mt][0]*inv, oacc[s][mt][1]*inv, oacc[s][mt][2]*inv, oacc[s][mt][3]*inv); \
        }                                                                         \
    }

#define COMMON_IDS()                                                              \
    const int tid  = threadIdx.x;                                                 \
    const int L    = tid & 63;                                                    \
    const int wv   = tid >> 6;                                                    \
    const int n16  = L & 15;                                                      \
    const int quad = L >> 4;                                                      \
    const int sw   = n16 & 7;                                                     \
    const int r4   = L >> 2;                                                      \
    const int c4   = L & 3;                                                       \
    int b, h, q0; dec_xcd(blockIdx.x, b, h, q0);                                  \
    const float4* QKV4 = (const float4*)QKV;

// ---------------------------------------------------------------------------
// Tier (a): both K and V tiles DMA'd, double-buffered, 1 barrier/chunk.
// (Exact R0 shell - validated at 107-108 us.)
// ---------------------------------------------------------------------------
__global__ __launch_bounds__(256, 3)
void attn_full(const float* __restrict__ QKV,
               const float* __restrict__ q_scale,
               const float* __restrict__ q_bias,
               const unsigned char* __restrict__ ws,
               float* __restrict__ out)
{
    __shared__ __align__(16) unsigned char sm[49152]; // 2x(Ka8K|Vt8K) + Qt/P 16K
    COMMON_IDS()
    unsigned char* Qt = sm + 32768;
    unsigned char* Pw = Qt + wv*4096;

    const unsigned char* Ktiles = ws + (size_t)((b*NH + h)*NCH) * TILE_B;
    const unsigned char* Vtiles = ws + KT_BYTES + (size_t)((b*NH + h)*NCH) * TILE_B;

    #define ISSUE_KV(MC, P)                                                       \
    {                                                                             \
        const unsigned char* kt_ = Ktiles + (size_t)(MC) * TILE_B;                \
        const unsigned char* vt_ = Vtiles + (size_t)(MC) * TILE_B;                \
        unsigned char* lk_ = sm + (P)*16384;                                      \
        unsigned char* lv_ = lk_ + 8192;                                          \
        _Pragma("unroll")                                                         \
        for (int t_ = 0; t_ < 2; ++t_) {                                          \
            int seg_ = wv*2 + t_;                                                 \
            __builtin_amdgcn_global_load_lds((const AS1 u32*)(kt_ + seg_*1024 + L*16), \
                                             (AS3 u32*)(lk_ + seg_*1024), 16, 0, 0);   \
            __builtin_amdgcn_global_load_lds((const AS1 u32*)(vt_ + seg_*1024 + L*16), \
                                             (AS3 u32*)(lv_ + seg_*1024), 16, 0, 0);   \
        }                                                                         \
    }

    ISSUE_KV(0, 0)
    Q_PROLOGUE(Qt)

    f32x4 oacc[2][4] = {};
    float lsum[2] = {0.f, 0.f};

    for (int mc = 0; mc < NCH; ++mc) {
        const int p = mc & 1;
        __syncthreads();                       // DMA(mc) landed; buf p^1 reads done
        if (mc + 1 < NCH) ISSUE_KV(mc + 1, p ^ 1)
        const unsigned char* Ka = sm + p*16384;
        const unsigned char* Vt = Ka + 8192;
        CHUNK_COMPUTE(Ka, Vt)
    }
    EPILOGUE()
    #undef ISSUE_KV
}

// ---------------------------------------------------------------------------
// Tier (b): K tiles DMA'd (dbuf), V staged in-kernel (R6 path), 2 barriers.
// ---------------------------------------------------------------------------
__global__ __launch_bounds__(256, 3)
void attn_ktile(const float* __restrict__ QKV,
                const float* __restrict__ q_scale,
                const float* __restrict__ q_bias,
                const unsigned char* __restrict__ ws,
                float* __restrict__ out)
{
    __shared__ __align__(16) unsigned char sm[40960]; // Kbuf0 8K|Kbuf1 8K|Vt 8K|Qt/P 16K
    COMMON_IDS()
    unsigned char* Vt = sm + 16384;
    unsigned char* Qt = sm + 24576;
    unsigned char* Pw = Qt + wv*4096;

    const unsigned char* Ktiles = ws + (size_t)((b*NH + h)*NCH) * TILE_B;

    #define ISSUE_K(MC, P)                                                        \
    {                                                                             \
        const unsigned char* kt_ = Ktiles + (size_t)(MC) * TILE_B;                \
        unsigned char* lk_ = sm + (P)*8192;                                       \
        _Pragma("unroll")                                                         \
        for (int t_ = 0; t_ < 2; ++t_) {                                          \
            int seg_ = wv*2 + t_;                                                 \
            __builtin_amdgcn_global_load_lds((const AS1 u32*)(kt_ + seg_*1024 + L*16), \
                                             (AS3 u32*)(lk_ + seg_*1024), 16, 0, 0);   \
        }                                                                         \
    }
    float vv[16];
    #define PREFETCH_V(MC)                                                        \
    {                                                                             \
        const float* gv = QKV + (size_t)(b*SEQ + (MC)*64 + wv*16) * CIN + 1536 + h*64 + L; \
        _Pragma("unroll")                                                         \
        for (int j = 0; j < 16; ++j) vv[j] = gv[(size_t)j * CIN];                 \
    }
    #define STAGE_V()                                                             \
    {                                                                             \
        half8 a0, a1;                                                             \
        _Pragma("unroll")                                                         \
        for (int j = 0; j < 8; ++j) { a0[j] = (_Float16)vv[j]; a1[j] = (_Float16)vv[j+8]; } \
        *(half8*)(Vt + L*128 + (((2*wv+0) ^ (L & 7)) * 16)) = a0;                 \
        *(half8*)(Vt + L*128 + (((2*wv+1) ^ (L & 7)) * 16)) = a1;                 \
    }

    PREFETCH_V(0)
    ISSUE_K(0, 0)
    Q_PROLOGUE(Qt)

    f32x4 oacc[2][4] = {};
    float lsum[2] = {0.f, 0.f};

    for (int mc = 0; mc < NCH; ++mc) {
        const int p = mc & 1;
        __syncthreads();                    // K-DMA(mc) landed; prev Vt reads done
        STAGE_V()
        __syncthreads();                    // Vt visible
        if (mc + 1 < NCH) { ISSUE_K(mc + 1, p ^ 1) PREFETCH_V(mc + 1) }
        const unsigned char* Ka = sm + p*8192;
        CHUNK_COMPUTE(Ka, Vt)
    }
    EPILOGUE()
    #undef ISSUE_K
    #undef PREFETCH_V
    #undef STAGE_V
}

// ---------------------------------------------------------------------------
// Tier (c) fallback: exact R6 fused kernel (validated).
// ---------------------------------------------------------------------------
__global__ __launch_bounds__(256, 3)
void fused_fallback(const float* __restrict__ QKV,
                    const float* __restrict__ q_scale,
                    const float* __restrict__ q_bias,
                    const float* __restrict__ k_scale,
                    const float* __restrict__ k_bias,
                    float* __restrict__ out)
{
    __shared__ __align__(16) unsigned char sm[32768];
    COMMON_IDS()
    unsigned char* Ka = sm;
    unsigned char* Vt = sm + 8192;
    unsigned char* Qt = sm + 16384;
    unsigned char* Pw = Qt + wv*4096;

    float4 ksr[4], kbr[4];
    #pragma unroll
    for (int i = 0; i < 4; ++i) {
        ksr[i] = ((const float4*)k_scale)[c4 * 4 + i];
        kbr[i] = ((const float4*)k_bias)[c4 * 4 + i];
    }
    float4 kx[4];
    float  vv[16];
    #define PREFETCH(MC)                                                          \
    {                                                                             \
        const size_t kb4 = (size_t)(b*SEQ + (MC)*64 + wv*16 + r4) * 576 + 192 + h*16 + c4*4; \
        _Pragma("unroll")                                                         \
        for (int i = 0; i < 4; ++i) kx[i] = QKV4[kb4 + i];                        \
        const float* gv = QKV + (size_t)(b*SEQ + (MC)*64 + wv*16) * CIN + 1536 + h*64 + L; \
        _Pragma("unroll")                                                         \
        for (int j = 0; j < 16; ++j) vv[j] = gv[(size_t)j * CIN];                 \
    }
    #define STAGE_KV()                                                            \
    {                                                                             \
        const int row = wv*16 + r4;                                               \
        float s = 0.f, s2 = 0.f;                                                  \
        _Pragma("unroll")                                                         \
        for (int i = 0; i < 4; ++i) {                                             \
            s  += kx[i].x + kx[i].y + kx[i].z + kx[i].w;                          \
            s2 += kx[i].x*kx[i].x + kx[i].y*kx[i].y + kx[i].z*kx[i].z + kx[i].w*kx[i].w; \
        }                                                                         \
        s  += __shfl_xor(s, 1);  s  += __shfl_xor(s, 2);                          \
        s2 += __shfl_xor(s2, 1); s2 += __shfl_xor(s2, 2);                         \
        float mu = s * 0.015625f;                                                 \
        float rstd = rsqrtf(s2 * 0.015625f - mu*mu + 1e-6f);                      \
        float nb0 = -mu * rstd;                                                   \
        half8 h0, h1;                                                             \
        _Pragma("unroll")                                                         \
        for (int i = 0; i < 4; ++i) {                                             \
            float e0 = fmaf(kx[i].x, rstd, nb0) * ksr[i].x + kbr[i].x;            \
            float e1 = fmaf(kx[i].y, rstd, nb0) * ksr[i].y + kbr[i].y;            \
            float e2 = fmaf(kx[i].z, rstd, nb0) * ksr[i].z + kbr[i].z;            \
            float e3 = fmaf(kx[i].w, rstd, nb0) * ksr[i].w + kbr[i].w;            \
            if (i < 2) { h0[i*4+0]=(_Float16)e0; h0[i*4+1]=(_Float16)e1; h0[i*4+2]=(_Float16)e2; h0[i*4+3]=(_Float16)e3; } \
            else { int j=(i-2)*4; h1[j+0]=(_Float16)e0; h1[j+1]=(_Float16)e1; h1[j+2]=(_Float16)e2; h1[j+3]=(_Float16)e3; } \
        }                                                                         \
        *(half8*)(Ka + row*128 + (((2*c4+0) ^ (row & 7)) * 16)) = h0;             \
        *(half8*)(Ka + row*128 + (((2*c4+1) ^ (row & 7)) * 16)) = h1;             \
        half8 a0, a1;                                                             \
        _Pragma("unroll")                                                         \
        for (int j = 0; j < 8; ++j) { a0[j] = (_Float16)vv[j]; a1[j] = (_Float16)vv[j+8]; } \
        *(half8*)(Vt + L*128 + (((2*wv+0) ^ (L & 7)) * 16)) = a0;                 \
        *(half8*)(Vt + L*128 + (((2*wv+1) ^ (L & 7)) * 16)) = a1;                 \
    }

    PREFETCH(0)
    Q_PROLOGUE(Qt)

    f32x4 oacc[2][4] = {};
    float lsum[2] = {0.f, 0.f};

    for (int mc = 0; mc < NCH; ++mc) {
        __syncthreads();
        STAGE_KV()
        __syncthreads();
        if (mc + 1 < NCH) PREFETCH(mc + 1)
        CHUNK_COMPUTE(Ka, Vt)
    }
    EPILOGUE()
    #undef PREFETCH
    #undef STAGE_KV
}

extern "C" void kernel_launch(void* const* d_in, const int* in_sizes, int n_in,
                              void* d_out, int out_size, void* d_ws, size_t ws_size,
                              hipStream_t stream) {
    const float* QKV     = (const float*)d_in[0];
    const float* q_scale = (const float*)d_in[1];
    const float* q_bias  = (const float*)d_in[2];
    const float* k_scale = (const float*)d_in[3];
    const float* k_bias  = (const float*)d_in[4];
    float* out = (float*)d_out;
    unsigned char* ws = (unsigned char*)d_ws;

    const dim3 agrid(NB * NH * (SEQ / TQ));   // 768 flat, XCD-decoded inside
    if (ws_size >= WS_FULL) {
        preprocess_kernel<<<dim3(NCH, NH, NB), 256, 0, stream>>>(QKV, k_scale, k_bias, ws, 1);
        attn_full<<<agrid, 256, 0, stream>>>(QKV, q_scale, q_bias, ws, out);
    } else if (ws_size >= KT_BYTES) {
        preprocess_kernel<<<dim3(NCH, NH, NB), 256, 0, stream>>>(QKV, k_scale, k_bias, ws, 0);
        attn_ktile<<<agrid, 256, 0, stream>>>(QKV, q_scale, q_bias, ws, out);
    } else {
        fused_fallback<<<agrid, 256, 0, stream>>>(QKV, q_scale, q_bias, k_scale, k_bias, out);
    }
}